// Round 1
// baseline (2037.263 us; speedup 1.0000x reference)
//
#include <hip/hip_runtime.h>
#include <math.h>

#define NN 50000
#define DD 128
#define HH 4
#define DHH 32
#define EE 600000

__device__ __forceinline__ float lrelu(float v){ return v > 0.f ? v : 0.2f*v; }
__device__ __forceinline__ float gelu_exact(float x){ return 0.5f*x*(1.f+erff(x*0.70710678118654752f)); }

// ---------------- FiLM (tiny) ----------------
__global__ void film_kernel(const float* __restrict__ z, const float* __restrict__ W1, const float* __restrict__ b1,
                            const float* __restrict__ W2, const float* __restrict__ b2, float* __restrict__ gb){
  __shared__ float hsh[256];
  int j = threadIdx.x;
  float acc = b1[j];
  for(int d=0; d<DD; ++d) acc = fmaf(z[d], W1[d*256+j], acc);
  hsh[j] = gelu_exact(acc);
  __syncthreads();
  float acc2 = b2[j];
  for(int k=0;k<256;++k) acc2 = fmaf(hsh[k], W2[k*256+j], acc2);
  gb[j] = acc2;
}

// ---------------- CSR build ----------------
__global__ void count_kernel(const int* __restrict__ dst, int* __restrict__ cnt, int ne){
  int e = blockIdx.x*blockDim.x+threadIdx.x;
  if(e<ne) atomicAdd(&cnt[dst[e]],1);
}

__global__ void scan_kernel(const int* __restrict__ cnt, int* __restrict__ row_start, int* __restrict__ cursor, int n){
  __shared__ int sums[1024];
  int t = threadIdx.x;
  int chunk = (n+1023)>>10;
  int lo = t*chunk, hi = min(lo+chunk, n);
  int s=0;
  for(int i=lo;i<hi;++i) s += cnt[i];
  sums[t]=s;
  __syncthreads();
  for(int off=1; off<1024; off<<=1){
    int v = (t>=off)? sums[t-off] : 0;
    __syncthreads();
    sums[t] += v;
    __syncthreads();
  }
  int prefix = (t==0)? 0 : sums[t-1];
  for(int i=lo;i<hi;++i){
    row_start[i]=prefix; cursor[i]=prefix; prefix += cnt[i];
  }
  if(t==1023) row_start[n] = sums[1023];
}

__global__ void fill_kernel(const int* __restrict__ src, const int* __restrict__ dst, int* __restrict__ cursor,
                            int2* __restrict__ elist, int ne){
  int e = blockIdx.x*blockDim.x+threadIdx.x;
  if(e<ne){
    int d = dst[e];
    int pos = atomicAdd(&cursor[d],1);
    elist[pos] = make_int2(src[e], e);
  }
}

// ---------------- GEMM: C[n,128] = A[n,128] @ W[128,128] (+bias, +gelu(A), +film epilogue) ----------------
constexpr int GM_GELU_A = 1;
constexpr int GM_BIAS   = 2;
constexpr int GM_FILM   = 4;

template<int MODE>
__global__ __launch_bounds__(256) void gemm128(const float* __restrict__ A, const float* __restrict__ Wg,
    const float* __restrict__ bias, const float* __restrict__ base, const float* __restrict__ fgb,
    float* __restrict__ C, int n){
  __shared__ float As[32][128];
  const int tid = threadIdx.x;
  const int row0 = blockIdx.x*32;
  {
    const float4* Ag = (const float4*)(A + (size_t)row0*DD);
    float4* As4 = (float4*)&As[0][0];
    const int maxv = (min(32, n-row0))*32;   // float4 count
    #pragma unroll
    for(int j=0;j<4;++j){
      int v = tid + j*256;
      float4 val = make_float4(0.f,0.f,0.f,0.f);
      if(v < maxv) val = Ag[v];
      if(MODE & GM_GELU_A){
        val.x = gelu_exact(val.x); val.y = gelu_exact(val.y);
        val.z = gelu_exact(val.z); val.w = gelu_exact(val.w);
      }
      As4[v] = val;
    }
  }
  __syncthreads();
  const int c2 = tid & 63;   // column pair
  const int rh = tid >> 6;   // row group (8 rows each), wave-uniform
  float acc[8][2];
  #pragma unroll
  for(int r=0;r<8;++r){ acc[r][0]=0.f; acc[r][1]=0.f; }
  #pragma unroll 8
  for(int k=0;k<128;++k){
    const float2 w = *(const float2*)&Wg[k*128 + 2*c2];
    #pragma unroll
    for(int r=0;r<8;++r){
      const float a = As[rh*8+r][k];
      acc[r][0] = fmaf(a, w.x, acc[r][0]);
      acc[r][1] = fmaf(a, w.y, acc[r][1]);
    }
  }
  const int c = 2*c2;
  float b0=0.f, b1=0.f;
  if(MODE & GM_BIAS){ b0 = bias[c]; b1 = bias[c+1]; }
  #pragma unroll
  for(int r=0;r<8;++r){
    int row = row0 + rh*8 + r;
    if(row < n){
      float o0 = acc[r][0]+b0, o1 = acc[r][1]+b1;
      if(MODE & GM_FILM){
        o0 += base[(size_t)row*DD + c];
        o1 += base[(size_t)row*DD + c + 1];
        o0 = fgb[c]*o0 + fgb[128+c];
        o1 = fgb[c+1]*o1 + fgb[128+c+1];
      }
      C[(size_t)row*DD + c]   = o0;
      C[(size_t)row*DD + c+1] = o1;
    }
  }
}

// ---------------- GAT pieces ----------------
__global__ void init_bias2(float* __restrict__ acc, const float* __restrict__ b0, const float* __restrict__ b1){
  int idx = blockIdx.x*blockDim.x+threadIdx.x;
  if(idx < NN*DD){ int c = idx & 127; acc[idx] = b0[c]+b1[c]; }
}

__global__ void att_logits_kernel(const float* __restrict__ xp, const float* __restrict__ a_s,
                                  const float* __restrict__ a_d, float* __restrict__ al_s, float* __restrict__ al_d){
  int idx = blockIdx.x*blockDim.x+threadIdx.x;
  if(idx >= NN*HH) return;
  int h = idx & 3;
  int node = idx >> 2;
  const float4* row = (const float4*)(xp + (size_t)node*DD + h*DHH);
  const float4* as4 = (const float4*)(a_s + h*DHH);
  const float4* ad4 = (const float4*)(a_d + h*DHH);
  float s1=0.f, s2=0.f;
  #pragma unroll
  for(int d=0; d<8; ++d){
    float4 v = row[d], va = as4[d], vd = ad4[d];
    s1 += v.x*va.x + v.y*va.y + v.z*va.z + v.w*va.w;
    s2 += v.x*vd.x + v.y*vd.y + v.z*vd.z + v.w*vd.w;
  }
  al_s[idx]=s1; al_d[idx]=s2;
}

// one wave per node; lane owns features (2*lane, 2*lane+1); head = lane>>4
__global__ __launch_bounds__(256) void gat_gather_kernel(const float* __restrict__ xp, const float* __restrict__ al_s,
    const float* __restrict__ al_d, const int* __restrict__ row_start, const int2* __restrict__ elist,
    float* __restrict__ acc_out){
  const int gid = blockIdx.x*blockDim.x + threadIdx.x;
  const int node = gid >> 6;
  const int lane = threadIdx.x & 63;
  if(node >= NN) return;
  const int h = lane >> 4;
  const int s0 = row_start[node], s1 = row_start[node+1];
  const float ald = al_d[node*4+h];
  float ssum = 0.f, a0=0.f, a1=0.f;
  for(int p=s0; p<s1; ++p){
    const int2 se = elist[p];
    float lg = al_s[se.x*4+h] + ald;
    lg = lg>0.f? lg : 0.2f*lg;
    const float ev = __expf(lg);
    ssum += ev;
    const float2 xr = *(const float2*)&xp[(size_t)se.x*DD + 2*lane];
    a0 = fmaf(ev, xr.x, a0); a1 = fmaf(ev, xr.y, a1);
  }
  { // self loop (appended in reference)
    float lg = al_s[node*4+h] + ald;
    lg = lg>0.f? lg : 0.2f*lg;
    const float ev = __expf(lg);
    ssum += ev;
    const float2 xr = *(const float2*)&xp[(size_t)node*DD + 2*lane];
    a0 = fmaf(ev, xr.x, a0); a1 = fmaf(ev, xr.y, a1);
  }
  const float inv = 1.f/ssum;
  float2 o = *(float2*)&acc_out[(size_t)node*DD + 2*lane];
  o.x += a0*inv; o.y += a1*inv;
  *(float2*)&acc_out[(size_t)node*DD + 2*lane] = o;
}

// ---------------- BN (deterministic two-stage) ----------------
__global__ void bn_stats(const float* __restrict__ X, float* __restrict__ part){
  int f = threadIdx.x & 127, rg = threadIdx.x>>7;
  float s=0.f, s2=0.f;
  for(int r = blockIdx.x*2+rg; r<NN; r += gridDim.x*2){
    float v = X[(size_t)r*DD+f]; s+=v; s2 = fmaf(v,v,s2);
  }
  __shared__ float ls[256], ls2[256];
  ls[threadIdx.x]=s; ls2[threadIdx.x]=s2; __syncthreads();
  if(rg==0){
    part[blockIdx.x*256 + f]       = ls[f]+ls[128+f];
    part[blockIdx.x*256 + 128 + f] = ls2[f]+ls2[128+f];
  }
}

__global__ void bn_finalize(const float* __restrict__ part, const float* __restrict__ gamma,
                            const float* __restrict__ beta, float* __restrict__ stat, int nblk){
  int f=threadIdx.x;
  float s=0.f, s2=0.f;
  for(int b=0;b<nblk;++b){ s+=part[b*256+f]; s2+=part[b*256+128+f]; }
  float mu = s/(float)NN;
  float var = s2/(float)NN - mu*mu;
  float rs = rsqrtf(var+1e-5f);
  stat[f]     = gamma[f]*rs;              // A
  stat[128+f] = beta[f] - gamma[f]*rs*mu; // B
}

// out = lrelu(xprev + A*acc + B)
__global__ void bn_apply_lrelu(const float* __restrict__ xprev, const float* __restrict__ acc,
                               const float* __restrict__ stat, float* __restrict__ out){
  int idx = blockIdx.x*blockDim.x+threadIdx.x;
  if(idx >= NN*DD) return;
  int c = idx & 127;
  float v = xprev[idx] + fmaf(stat[c], acc[idx], stat[128+c]);
  out[idx] = lrelu(v);
}

// ---------------- HGT pieces ----------------
// y[n,h,e] = sum_d x[n,h,d] * M[h,d,e]
__global__ __launch_bounds__(256) void head_transform_kernel(const float* __restrict__ X, const float* __restrict__ M,
    float* __restrict__ Y){
  __shared__ float Ms[HH*DHH*DHH];
  for(int i=threadIdx.x; i<HH*DHH*DHH; i+=blockDim.x) Ms[i]=M[i];
  __syncthreads();
  int idx = blockIdx.x*blockDim.x + threadIdx.x;
  if(idx >= NN*DD) return;
  int node = idx>>7, f = idx&127;
  int h=f>>5, e=f&31;
  const float* xr = X + (size_t)node*DD + h*DHH;
  const float* m = Ms + h*DHH*DHH + e;
  float s=0.f;
  #pragma unroll
  for(int d=0; d<DHH; ++d) s = fmaf(xr[d], m[d*DHH], s);
  Y[idx]=s;
}

// wave per node; 16 lanes per head cooperatively dot q[dst]·kt[src] over DH=32
__global__ __launch_bounds__(256) void hgt_logits_kernel(const float* __restrict__ q, const float* __restrict__ kt,
    const int* __restrict__ row_start, const int2* __restrict__ elist, const float* __restrict__ p_rel_t,
    float* __restrict__ e_buf_t, float* __restrict__ s_sum){
  const int gid = blockIdx.x*blockDim.x + threadIdx.x;
  const int node = gid >> 6;
  const int lane = threadIdx.x & 63;
  if(node >= NN) return;
  const int h = lane>>4, dp = (lane&15)*2;
  const float2 qv = *(const float2*)&q[(size_t)node*DD + h*DHH + dp];
  const float scale = p_rel_t[h]*0.17677669529663687f; // p_rel / sqrt(32)
  const int s0=row_start[node], s1=row_start[node+1];
  float ssum=0.f;
  for(int p=s0;p<s1;++p){
    const int2 se = elist[p];
    const float2 kv = *(const float2*)&kt[(size_t)se.x*DD + h*DHH + dp];
    float part = qv.x*kv.x + qv.y*kv.y;
    part += __shfl_xor(part,1);
    part += __shfl_xor(part,2);
    part += __shfl_xor(part,4);
    part += __shfl_xor(part,8);
    const float ev = __expf(part*scale);
    ssum += ev;
    if((lane&15)==0) e_buf_t[(size_t)se.y*4 + h] = ev;
  }
  if((lane&15)==0) s_sum[node*4+h] += ssum;
}

__global__ __launch_bounds__(256) void hgt_gather_kernel(const float* __restrict__ vt, const float* __restrict__ e_buf_t,
    const float* __restrict__ s_sum, const int* __restrict__ row_start, const int2* __restrict__ elist,
    float* __restrict__ agg){
  const int gid = blockIdx.x*blockDim.x + threadIdx.x;
  const int node = gid>>6;
  const int lane = threadIdx.x & 63;
  if(node >= NN) return;
  const int h = lane>>4;
  const int s0=row_start[node], s1=row_start[node+1];
  if(s0==s1) return;               // no edges of this type: nothing to add (agg pre-zeroed)
  float a0=0.f, a1=0.f;
  for(int p=s0;p<s1;++p){
    const int2 se = elist[p];
    const float ev = e_buf_t[(size_t)se.y*4+h];
    const float2 vv = *(const float2*)&vt[(size_t)se.x*DD + 2*lane];
    a0 = fmaf(ev, vv.x, a0); a1 = fmaf(ev, vv.y, a1);
  }
  const float inv = 1.f/s_sum[node*4+h];  // >0: this type contributed at least one exp()
  float2 o = *(float2*)&agg[(size_t)node*DD + 2*lane];
  o.x += a0*inv; o.y += a1*inv;
  *(float2*)&agg[(size_t)node*DD + 2*lane] = o;
}

// x3a = sigmoid(skip)*hgt_out + (1-sigmoid(skip))*x2
__global__ void skip_mix(const float* __restrict__ hgt_out, const float* __restrict__ x2,
                         const float* __restrict__ skip_s, float* __restrict__ out){
  int idx = blockIdx.x*blockDim.x+threadIdx.x;
  if(idx >= NN*DD) return;
  float sk = 1.f/(1.f+__expf(-skip_s[0]));
  out[idx] = sk*hgt_out[idx] + (1.f-sk)*x2[idx];
}

// ---------------- host ----------------
extern "C" void kernel_launch(void* const* d_in, const int* in_sizes, int n_in,
                              void* d_out, int out_size, void* d_ws, size_t ws_size,
                              hipStream_t stream){
  const float* x_cell = (const float*)d_in[0];
  const float* z_h    = (const float*)d_in[1];
  const float* x_emb  = (const float*)d_in[2];
  const int*   ei0    = (const int*)d_in[3];
  const int*   ei1    = (const int*)d_in[4];
  const float* gat_W  = (const float*)d_in[5];
  const float* gat_as = (const float*)d_in[6];
  const float* gat_ad = (const float*)d_in[7];
  const float* gat_b  = (const float*)d_in[8];
  const float* bn_g   = (const float*)d_in[9];
  const float* bn_b   = (const float*)d_in[10];
  const float* Wk = (const float*)d_in[11];
  const float* bk = (const float*)d_in[12];
  const float* Wq = (const float*)d_in[13];
  const float* bq = (const float*)d_in[14];
  const float* Wv = (const float*)d_in[15];
  const float* bv = (const float*)d_in[16];
  const float* a_rel = (const float*)d_in[17];
  const float* m_rel = (const float*)d_in[18];
  const float* p_rel = (const float*)d_in[19];
  const float* Wo = (const float*)d_in[20];
  const float* bo = (const float*)d_in[21];
  const float* skip = (const float*)d_in[22];
  const float* injW = (const float*)d_in[23];
  const float* injb = (const float*)d_in[24];
  const float* fW1 = (const float*)d_in[25];
  const float* fb1 = (const float*)d_in[26];
  const float* fW2 = (const float*)d_in[27];
  const float* fb2 = (const float*)d_in[28];

  constexpr size_t SLOT = (size_t)NN*DD;   // 6,400,000 floats
  float* ws = (float*)d_ws;
  float* W0 = ws;
  float* W1 = W0 + SLOT;
  float* W2 = W1 + SLOT;
  float* W3 = W2 + SLOT;
  float* ebuf   = W3 + SLOT;            // 2*E*H = 4,800,000
  float* als    = ebuf + (size_t)2*EE*HH;
  float* ald    = als + (size_t)NN*HH;
  float* ssum   = ald + (size_t)NN*HH;
  float* bnpart = ssum + (size_t)NN*HH; // 256*256
  float* bnstat = bnpart + 256*256;     // 256
  float* fgb    = bnstat + 256;         // 256
  int* iws = (int*)(fgb + 256);
  int* cnt0 = iws;
  int* rs0  = cnt0 + NN;
  int* cur0 = rs0 + (NN+2);
  int2* el0 = (int2*)(cur0 + NN);
  int* cnt1 = (int*)(el0 + EE);
  int* rs1  = cnt1 + NN;
  int* cur1 = rs1 + (NN+2);
  int2* el1 = (int2*)(cur1 + NN);
  size_t needed = (size_t)((char*)(el1 + EE) - (char*)d_ws);
  if(ws_size < needed) return;  // insufficient scratch: fail loud (poisoned d_out)

  const int TB = 256;
  dim3 b(TB);
  const int gE     = (EE + TB - 1)/TB;
  const int gND    = (NN*DD + TB - 1)/TB;
  const int gNH    = (NN*HH + TB - 1)/TB;
  const int gNodes = (NN + 3)/4;          // 4 waves/block, wave per node
  const int gGemm  = (NN + 31)/32;

  // FiLM params (only depend on z_h)
  film_kernel<<<1, 256, 0, stream>>>(z_h, fW1, fb1, fW2, fb2, fgb);

  // CSR by dst for both edge types (src stored alongside original edge id)
  hipMemsetAsync(cnt0, 0, NN*sizeof(int), stream);
  hipMemsetAsync(cnt1, 0, NN*sizeof(int), stream);
  count_kernel<<<gE, b, 0, stream>>>(ei0+EE, cnt0, EE);
  count_kernel<<<gE, b, 0, stream>>>(ei1+EE, cnt1, EE);
  scan_kernel<<<1, 1024, 0, stream>>>(cnt0, rs0, cur0, NN);
  scan_kernel<<<1, 1024, 0, stream>>>(cnt1, rs1, cur1, NN);
  fill_kernel<<<gE, b, 0, stream>>>(ei0, ei0+EE, cur0, el0, EE);
  fill_kernel<<<gE, b, 0, stream>>>(ei1, ei1+EE, cur1, el1, EE);

  // ---- 2 hetero-GAT layers ----
  const float* xin = x_cell;
  for(int c=0;c<2;++c){
    init_bias2<<<gND, b, 0, stream>>>(W0, gat_b + (size_t)(c*2+0)*DD, gat_b + (size_t)(c*2+1)*DD);
    for(int t=0;t<2;++t){
      const int* rs = t? rs1:rs0; const int2* el = t? el1:el0;
      gemm128<0><<<gGemm, b, 0, stream>>>(xin, gat_W + (size_t)(c*2+t)*DD*DD,
                                          nullptr, nullptr, nullptr, W1, NN);
      att_logits_kernel<<<gNH, b, 0, stream>>>(W1, gat_as + (size_t)(c*2+t)*HH*DHH,
                                               gat_ad + (size_t)(c*2+t)*HH*DHH, als, ald);
      gat_gather_kernel<<<gNodes, b, 0, stream>>>(W1, als, ald, rs, el, W0);
    }
    bn_stats<<<256, b, 0, stream>>>(W0, bnpart);
    bn_finalize<<<1, 128, 0, stream>>>(bnpart, bn_g + (size_t)c*DD, bn_b + (size_t)c*DD, bnstat, 256);
    float* xout = (c==0)? W2 : W1;   // x1 -> W2 ; x2 -> W1 (xp dead by then)
    bn_apply_lrelu<<<gND, b, 0, stream>>>(xin, W0, bnstat, xout);
    xin = xout;
  }
  float* x2 = W1;

  // ---- HGT ----
  gemm128<GM_BIAS><<<gGemm, b, 0, stream>>>(x2, Wk, bk, nullptr, nullptr, W2, NN); // k
  gemm128<GM_BIAS><<<gGemm, b, 0, stream>>>(x2, Wq, bq, nullptr, nullptr, W0, NN); // q
  hipMemsetAsync(ssum, 0, (size_t)NN*HH*sizeof(float), stream);
  for(int t=0;t<2;++t){
    head_transform_kernel<<<gND, b, 0, stream>>>(W2, a_rel + (size_t)t*HH*DHH*DHH, W3); // kt
    hgt_logits_kernel<<<gNodes, b, 0, stream>>>(W0, W3, t?rs1:rs0, t?el1:el0,
                                                p_rel + (size_t)t*HH, ebuf + (size_t)t*EE*HH, ssum);
  }
  float* agg = (float*)d_out;
  hipMemsetAsync(agg, 0, (size_t)NN*DD*sizeof(float), stream);
  gemm128<GM_BIAS><<<gGemm, b, 0, stream>>>(x2, Wv, bv, nullptr, nullptr, W2, NN); // v (k dead)
  for(int t=0;t<2;++t){
    head_transform_kernel<<<gND, b, 0, stream>>>(W2, m_rel + (size_t)t*HH*DHH*DHH, W3); // vt
    hgt_gather_kernel<<<gNodes, b, 0, stream>>>(W3, ebuf + (size_t)t*EE*HH, ssum,
                                                t?rs1:rs0, t?el1:el0, agg);
  }
  gemm128<GM_BIAS|GM_GELU_A><<<gGemm, b, 0, stream>>>(agg, Wo, bo, nullptr, nullptr, W2, NN); // hgt_out
  skip_mix<<<gND, b, 0, stream>>>(W2, x2, skip, W3);                  // x3a
  bn_stats<<<256, b, 0, stream>>>(W3, bnpart);
  bn_finalize<<<1, 128, 0, stream>>>(bnpart, bn_g + 2*DD, bn_b + 2*DD, bnstat, 256);
  bn_apply_lrelu<<<gND, b, 0, stream>>>(x2, W3, bnstat, W3);          // x3c (in place, elementwise)
  // out = gamma * (x3c + x_emb@injW + injb) + beta
  gemm128<GM_BIAS|GM_FILM><<<gGemm, b, 0, stream>>>(x_emb, injW, injb, W3, fgb, (float*)d_out, NN);
}

// Round 2
// 1529.507 us; speedup vs baseline: 1.3320x; 1.3320x over previous
//
#include <hip/hip_runtime.h>
#include <math.h>

#define NN 50000
#define DD 128
#define HH 4
#define DHH 32
#define EE 600000

typedef unsigned short u16;
typedef unsigned int   u32;

__device__ __forceinline__ float lrelu(float v){ return v > 0.f ? v : 0.2f*v; }
__device__ __forceinline__ float gelu_exact(float x){ return 0.5f*x*(1.f+erff(x*0.70710678118654752f)); }
__device__ __forceinline__ u16 f2bf(float f){
  u32 u = __float_as_uint(f);
  u32 r = (u + 0x7fffu + ((u>>16)&1u)) >> 16;
  return (u16)r;
}
__device__ __forceinline__ float bflo(u32 u){ return __uint_as_float(u<<16); }
__device__ __forceinline__ float bfhi(u32 u){ return __uint_as_float(u & 0xffff0000u); }

// ---------------- FiLM (tiny) ----------------
__global__ void film_kernel(const float* __restrict__ z, const float* __restrict__ W1, const float* __restrict__ b1,
                            const float* __restrict__ W2, const float* __restrict__ b2, float* __restrict__ gb){
  __shared__ float hsh[256];
  int j = threadIdx.x;
  float acc = b1[j];
  for(int d=0; d<DD; ++d) acc = fmaf(z[d], W1[d*256+j], acc);
  hsh[j] = gelu_exact(acc);
  __syncthreads();
  float acc2 = b2[j];
  for(int k=0;k<256;++k) acc2 = fmaf(hsh[k], W2[k*256+j], acc2);
  gb[j] = acc2;
}

// ---------------- CSR build ----------------
__global__ void count_kernel(const int* __restrict__ dst, int* __restrict__ cnt, int ne){
  int e = blockIdx.x*blockDim.x+threadIdx.x;
  if(e<ne) atomicAdd(&cnt[dst[e]],1);
}

__global__ void scan_kernel(const int* __restrict__ cnt, int* __restrict__ row_start, int* __restrict__ cursor, int n){
  __shared__ int sums[1024];
  int t = threadIdx.x;
  int chunk = (n+1023)>>10;
  int lo = t*chunk, hi = min(lo+chunk, n);
  int s=0;
  for(int i=lo;i<hi;++i) s += cnt[i];
  sums[t]=s;
  __syncthreads();
  for(int off=1; off<1024; off<<=1){
    int v = (t>=off)? sums[t-off] : 0;
    __syncthreads();
    sums[t] += v;
    __syncthreads();
  }
  int prefix = (t==0)? 0 : sums[t-1];
  for(int i=lo;i<hi;++i){
    row_start[i]=prefix; cursor[i]=prefix; prefix += cnt[i];
  }
  if(t==1023) row_start[n] = sums[1023];
}

__global__ void fill_kernel(const int* __restrict__ src, const int* __restrict__ dst, int* __restrict__ cursor,
                            int* __restrict__ esrc, int ne){
  int e = blockIdx.x*blockDim.x+threadIdx.x;
  if(e<ne){
    int d = dst[e];
    int pos = atomicAdd(&cursor[d],1);
    esrc[pos] = src[e];
  }
}

// ---------------- GEMM: C[n,128] = A[n,128] @ W[128,128] (+bias, +gelu(A), +film, +bf16 out) ----------------
constexpr int GM_GELU_A = 1;
constexpr int GM_BIAS   = 2;
constexpr int GM_FILM   = 4;
constexpr int GM_BF16   = 8;

template<int MODE>
__global__ __launch_bounds__(256) void gemm128(const float* __restrict__ A, const float* __restrict__ Wg,
    const float* __restrict__ bias, const float* __restrict__ base, const float* __restrict__ fgb,
    void* __restrict__ Cv, int n){
  __shared__ float As[32][128];
  const int tid = threadIdx.x;
  const int row0 = blockIdx.x*32;
  {
    const float4* Ag = (const float4*)(A + (size_t)row0*DD);
    float4* As4 = (float4*)&As[0][0];
    const int maxv = (min(32, n-row0))*32;   // float4 count
    #pragma unroll
    for(int j=0;j<4;++j){
      int v = tid + j*256;
      float4 val = make_float4(0.f,0.f,0.f,0.f);
      if(v < maxv) val = Ag[v];
      if(MODE & GM_GELU_A){
        val.x = gelu_exact(val.x); val.y = gelu_exact(val.y);
        val.z = gelu_exact(val.z); val.w = gelu_exact(val.w);
      }
      As4[v] = val;
    }
  }
  __syncthreads();
  const int c2 = tid & 63;   // column pair
  const int rh = tid >> 6;   // row group (8 rows each), wave-uniform
  float acc[8][2];
  #pragma unroll
  for(int r=0;r<8;++r){ acc[r][0]=0.f; acc[r][1]=0.f; }
  #pragma unroll 8
  for(int k=0;k<128;++k){
    const float2 w = *(const float2*)&Wg[k*128 + 2*c2];
    #pragma unroll
    for(int r=0;r<8;++r){
      const float a = As[rh*8+r][k];
      acc[r][0] = fmaf(a, w.x, acc[r][0]);
      acc[r][1] = fmaf(a, w.y, acc[r][1]);
    }
  }
  const int c = 2*c2;
  float b0=0.f, b1=0.f;
  if(MODE & GM_BIAS){ b0 = bias[c]; b1 = bias[c+1]; }
  #pragma unroll
  for(int r=0;r<8;++r){
    int row = row0 + rh*8 + r;
    if(row < n){
      float o0 = acc[r][0]+b0, o1 = acc[r][1]+b1;
      if(MODE & GM_FILM){
        o0 += base[(size_t)row*DD + c];
        o1 += base[(size_t)row*DD + c + 1];
        o0 = fgb[c]*o0 + fgb[128+c];
        o1 = fgb[c+1]*o1 + fgb[128+c+1];
      }
      if(MODE & GM_BF16){
        u16* C = (u16*)Cv;
        ((u32*)&C[(size_t)row*DD + c])[0] = (u32)f2bf(o0) | ((u32)f2bf(o1)<<16);
      } else {
        float* C = (float*)Cv;
        C[(size_t)row*DD + c]   = o0;
        C[(size_t)row*DD + c+1] = o1;
      }
    }
  }
}

// ---------------- GAT pieces ----------------
__global__ void init_bias2(float* __restrict__ acc, const float* __restrict__ b0, const float* __restrict__ b1){
  int idx = blockIdx.x*blockDim.x+threadIdx.x;
  if(idx < NN*DD){ int c = idx & 127; acc[idx] = b0[c]+b1[c]; }
}

__global__ void att_logits_kernel(const float* __restrict__ xp, const float* __restrict__ a_s,
                                  const float* __restrict__ a_d, float* __restrict__ al_s, float* __restrict__ al_d){
  int idx = blockIdx.x*blockDim.x+threadIdx.x;
  if(idx >= NN*HH) return;
  int h = idx & 3;
  int node = idx >> 2;
  const float4* row = (const float4*)(xp + (size_t)node*DD + h*DHH);
  const float4* as4 = (const float4*)(a_s + h*DHH);
  const float4* ad4 = (const float4*)(a_d + h*DHH);
  float s1=0.f, s2=0.f;
  #pragma unroll
  for(int d=0; d<8; ++d){
    float4 v = row[d], va = as4[d], vd = ad4[d];
    s1 += v.x*va.x + v.y*va.y + v.z*va.z + v.w*va.w;
    s2 += v.x*vd.x + v.y*vd.y + v.z*vd.z + v.w*vd.w;
  }
  al_s[idx]=s1; al_d[idx]=s2;
}

// one wave per node; lane owns features (2*lane, 2*lane+1); head = lane>>4
__global__ __launch_bounds__(256) void gat_gather_kernel(const float* __restrict__ xp, const float* __restrict__ al_s,
    const float* __restrict__ al_d, const int* __restrict__ row_start, const int* __restrict__ esrc,
    float* __restrict__ acc_out){
  const int gid = blockIdx.x*blockDim.x + threadIdx.x;
  const int node = gid >> 6;
  const int lane = threadIdx.x & 63;
  if(node >= NN) return;
  const int h = lane >> 4;
  const int s0 = row_start[node], s1 = row_start[node+1];
  const float ald = al_d[node*4+h];
  float ssum = 0.f, a0=0.f, a1=0.f;
  int p = s0;
  for(; p+1<s1; p+=2){
    const int sA = esrc[p], sB = esrc[p+1];
    const float2 xA = *(const float2*)&xp[(size_t)sA*DD + 2*lane];
    const float2 xB = *(const float2*)&xp[(size_t)sB*DD + 2*lane];
    float lA = al_s[sA*4+h] + ald;  lA = lA>0.f? lA : 0.2f*lA;
    float lB = al_s[sB*4+h] + ald;  lB = lB>0.f? lB : 0.2f*lB;
    const float evA = __expf(lA), evB = __expf(lB);
    ssum += evA + evB;
    a0 = fmaf(evA, xA.x, a0); a1 = fmaf(evA, xA.y, a1);
    a0 = fmaf(evB, xB.x, a0); a1 = fmaf(evB, xB.y, a1);
  }
  if(p < s1){
    const int sA = esrc[p];
    const float2 xA = *(const float2*)&xp[(size_t)sA*DD + 2*lane];
    float lA = al_s[sA*4+h] + ald;  lA = lA>0.f? lA : 0.2f*lA;
    const float evA = __expf(lA);
    ssum += evA;
    a0 = fmaf(evA, xA.x, a0); a1 = fmaf(evA, xA.y, a1);
  }
  { // self loop (appended in reference)
    float lg = al_s[node*4+h] + ald;
    lg = lg>0.f? lg : 0.2f*lg;
    const float ev = __expf(lg);
    ssum += ev;
    const float2 xr = *(const float2*)&xp[(size_t)node*DD + 2*lane];
    a0 = fmaf(ev, xr.x, a0); a1 = fmaf(ev, xr.y, a1);
  }
  const float inv = 1.f/ssum;
  float2 o = *(float2*)&acc_out[(size_t)node*DD + 2*lane];
  o.x += a0*inv; o.y += a1*inv;
  *(float2*)&acc_out[(size_t)node*DD + 2*lane] = o;
}

// ---------------- BN (deterministic two-stage) ----------------
__global__ void bn_stats(const float* __restrict__ X, float* __restrict__ part){
  int f = threadIdx.x & 127, rg = threadIdx.x>>7;
  float s=0.f, s2=0.f;
  for(int r = blockIdx.x*2+rg; r<NN; r += gridDim.x*2){
    float v = X[(size_t)r*DD+f]; s+=v; s2 = fmaf(v,v,s2);
  }
  __shared__ float ls[256], ls2[256];
  ls[threadIdx.x]=s; ls2[threadIdx.x]=s2; __syncthreads();
  if(rg==0){
    part[blockIdx.x*256 + f]       = ls[f]+ls[128+f];
    part[blockIdx.x*256 + 128 + f] = ls2[f]+ls2[128+f];
  }
}

__global__ void bn_finalize(const float* __restrict__ part, const float* __restrict__ gamma,
                            const float* __restrict__ beta, float* __restrict__ stat, int nblk){
  int f=threadIdx.x;
  float s=0.f, s2=0.f;
  for(int b=0;b<nblk;++b){ s+=part[b*256+f]; s2+=part[b*256+128+f]; }
  float mu = s/(float)NN;
  float var = s2/(float)NN - mu*mu;
  float rs = rsqrtf(var+1e-5f);
  stat[f]     = gamma[f]*rs;              // A
  stat[128+f] = beta[f] - gamma[f]*rs*mu; // B
}

// out = lrelu(xprev + A*acc + B)
__global__ void bn_apply_lrelu(const float* __restrict__ xprev, const float* __restrict__ acc,
                               const float* __restrict__ stat, float* __restrict__ out){
  int idx = blockIdx.x*blockDim.x+threadIdx.x;
  if(idx >= NN*DD) return;
  int c = idx & 127;
  float v = xprev[idx] + fmaf(stat[c], acc[idx], stat[128+c]);
  out[idx] = lrelu(v);
}

// ---------------- HGT pieces ----------------
// fold a_rel/m_rel into projection weights:
// Wc[c][h*32+e] = sum_d Wsrc[c][h*32+d] * rel[h][d][e]; row c==128 is the bias.
__global__ void combine_weights(const float* __restrict__ Wsrc, const float* __restrict__ bsrc,
                                const float* __restrict__ rel, float* __restrict__ Wc, float* __restrict__ bc){
  __shared__ float rels[HH*DHH*DHH];
  for(int i=threadIdx.x;i<HH*DHH*DHH;i+=blockDim.x) rels[i]=rel[i];
  __syncthreads();
  int idx = blockIdx.x*blockDim.x+threadIdx.x;
  if(idx >= 129*128) return;
  int c = idx>>7, f = idx&127, h=f>>5, e=f&31;
  const float* srcp = (c<128)? &Wsrc[c*128 + h*DHH] : &bsrc[h*DHH];
  const float* m = &rels[h*DHH*DHH + e];
  float s=0.f;
  #pragma unroll
  for(int d=0;d<DHH;++d) s = fmaf(srcp[d], m[d*DHH], s);
  if(c<128) Wc[c*128+f]=s; else bc[f]=s;
}

// fused HGT edge phase for one edge type: logits + exp + weighted-V accumulate.
// FIRST=1: write raw acc + ssum. FIRST=0: add, normalize by total ssum, write final agg.
template<int FIRST>
__global__ __launch_bounds__(256) void hgt_fused_kernel(const float* __restrict__ q,
    const u16* __restrict__ ktb, const u16* __restrict__ vtb,
    const int* __restrict__ row_start, const int* __restrict__ esrc,
    const float* __restrict__ p_rel_t, float* __restrict__ acc, float* __restrict__ ssum_buf){
  const int gid = blockIdx.x*blockDim.x + threadIdx.x;
  const int node = gid >> 6;
  const int lane = threadIdx.x & 63;
  if(node >= NN) return;
  const int h = lane >> 4;              // 2*lane == h*32 + dp : q/kt/vt offset is just 2*lane
  const float2 qv = *(const float2*)&q[(size_t)node*DD + 2*lane];
  const float scale = p_rel_t[h]*0.17677669529663687f; // p_rel / sqrt(32)
  const int s0=row_start[node], s1=row_start[node+1];
  float ssum=0.f, a0=0.f, a1=0.f;
  int p=s0;
  for(; p+1<s1; p+=2){
    const int sA = esrc[p], sB = esrc[p+1];
    const u32 kA = *(const u32*)&ktb[(size_t)sA*DD + 2*lane];
    const u32 kB = *(const u32*)&ktb[(size_t)sB*DD + 2*lane];
    const u32 vA = *(const u32*)&vtb[(size_t)sA*DD + 2*lane];
    const u32 vB = *(const u32*)&vtb[(size_t)sB*DD + 2*lane];
    float pA = qv.x*bflo(kA) + qv.y*bfhi(kA);
    float pB = qv.x*bflo(kB) + qv.y*bfhi(kB);
    pA += __shfl_xor(pA,1); pB += __shfl_xor(pB,1);
    pA += __shfl_xor(pA,2); pB += __shfl_xor(pB,2);
    pA += __shfl_xor(pA,4); pB += __shfl_xor(pB,4);
    pA += __shfl_xor(pA,8); pB += __shfl_xor(pB,8);
    const float evA = __expf(pA*scale), evB = __expf(pB*scale);
    ssum += evA + evB;
    a0 = fmaf(evA, bflo(vA), a0); a1 = fmaf(evA, bfhi(vA), a1);
    a0 = fmaf(evB, bflo(vB), a0); a1 = fmaf(evB, bfhi(vB), a1);
  }
  if(p<s1){
    const int sA = esrc[p];
    const u32 kA = *(const u32*)&ktb[(size_t)sA*DD + 2*lane];
    const u32 vA = *(const u32*)&vtb[(size_t)sA*DD + 2*lane];
    float pA = qv.x*bflo(kA) + qv.y*bfhi(kA);
    pA += __shfl_xor(pA,1);
    pA += __shfl_xor(pA,2);
    pA += __shfl_xor(pA,4);
    pA += __shfl_xor(pA,8);
    const float evA = __expf(pA*scale);
    ssum += evA;
    a0 = fmaf(evA, bflo(vA), a0); a1 = fmaf(evA, bfhi(vA), a1);
  }
  if(FIRST){
    *(float2*)&acc[(size_t)node*DD + 2*lane] = make_float2(a0, a1);
    if((lane&15)==0) ssum_buf[node*4+h] = ssum;
  } else {
    const float tot = ssum + ssum_buf[node*4+h];
    const float inv = tot>0.f ? 1.f/tot : 0.f;
    float2 prev = *(float2*)&acc[(size_t)node*DD + 2*lane];
    prev.x = (prev.x + a0)*inv;
    prev.y = (prev.y + a1)*inv;
    *(float2*)&acc[(size_t)node*DD + 2*lane] = prev;
  }
}

// x3a = sigmoid(skip)*hgt_out + (1-sigmoid(skip))*x2
__global__ void skip_mix(const float* __restrict__ hgt_out, const float* __restrict__ x2,
                         const float* __restrict__ skip_s, float* __restrict__ out){
  int idx = blockIdx.x*blockDim.x+threadIdx.x;
  if(idx >= NN*DD) return;
  float sk = 1.f/(1.f+__expf(-skip_s[0]));
  out[idx] = sk*hgt_out[idx] + (1.f-sk)*x2[idx];
}

// ---------------- host ----------------
extern "C" void kernel_launch(void* const* d_in, const int* in_sizes, int n_in,
                              void* d_out, int out_size, void* d_ws, size_t ws_size,
                              hipStream_t stream){
  const float* x_cell = (const float*)d_in[0];
  const float* z_h    = (const float*)d_in[1];
  const float* x_emb  = (const float*)d_in[2];
  const int*   ei0    = (const int*)d_in[3];
  const int*   ei1    = (const int*)d_in[4];
  const float* gat_W  = (const float*)d_in[5];
  const float* gat_as = (const float*)d_in[6];
  const float* gat_ad = (const float*)d_in[7];
  const float* gat_b  = (const float*)d_in[8];
  const float* bn_g   = (const float*)d_in[9];
  const float* bn_b   = (const float*)d_in[10];
  const float* Wk = (const float*)d_in[11];
  const float* bk = (const float*)d_in[12];
  const float* Wq = (const float*)d_in[13];
  const float* bq = (const float*)d_in[14];
  const float* Wv = (const float*)d_in[15];
  const float* bv = (const float*)d_in[16];
  const float* a_rel = (const float*)d_in[17];
  const float* m_rel = (const float*)d_in[18];
  const float* p_rel = (const float*)d_in[19];
  const float* Wo = (const float*)d_in[20];
  const float* bo = (const float*)d_in[21];
  const float* skip = (const float*)d_in[22];
  const float* injW = (const float*)d_in[23];
  const float* injb = (const float*)d_in[24];
  const float* fW1 = (const float*)d_in[25];
  const float* fb1 = (const float*)d_in[26];
  const float* fW2 = (const float*)d_in[27];
  const float* fb2 = (const float*)d_in[28];

  constexpr size_t SLOT = (size_t)NN*DD;   // 6,400,000 floats
  float* ws = (float*)d_ws;
  float* W0 = ws;
  float* W1 = W0 + SLOT;
  float* W2 = W1 + SLOT;
  u16* ktb  = (u16*)(W2 + SLOT);        // NN*DD bf16
  u16* vtb  = ktb + SLOT;               // NN*DD bf16
  float* als    = (float*)(vtb + SLOT);
  float* ald    = als + (size_t)NN*HH;
  float* ssum   = ald + (size_t)NN*HH;
  float* bnpart = ssum + (size_t)NN*HH;
  float* bnstat = bnpart + 256*256;
  float* fgb    = bnstat + 256;
  float* wck    = fgb + 256;            // combined kt weights 128x128
  float* bck    = wck + 128*128;
  float* wcv    = bck + 128;
  float* bcv    = wcv + 128*128;
  int* iws = (int*)(bcv + 128);
  int* cnt0 = iws;
  int* rs0  = cnt0 + NN;
  int* cur0 = rs0 + (NN+2);
  int* es0  = cur0 + NN;
  int* cnt1 = es0 + EE;
  int* rs1  = cnt1 + NN;
  int* cur1 = rs1 + (NN+2);
  int* es1  = cur1 + NN;
  size_t needed = (size_t)((char*)(es1 + EE) - (char*)d_ws);
  if(ws_size < needed) return;  // insufficient scratch: fail loud (poisoned d_out)

  const int TB = 256;
  dim3 b(TB);
  const int gE     = (EE + TB - 1)/TB;
  const int gND    = (NN*DD + TB - 1)/TB;
  const int gNH    = (NN*HH + TB - 1)/TB;
  const int gNodes = (NN + 3)/4;          // 4 waves/block, wave per node
  const int gGemm  = (NN + 31)/32;
  const int gCW    = (129*128 + TB - 1)/TB;

  // FiLM params (only depend on z_h)
  film_kernel<<<1, 256, 0, stream>>>(z_h, fW1, fb1, fW2, fb2, fgb);

  // CSR by dst for both edge types (src only)
  hipMemsetAsync(cnt0, 0, NN*sizeof(int), stream);
  hipMemsetAsync(cnt1, 0, NN*sizeof(int), stream);
  count_kernel<<<gE, b, 0, stream>>>(ei0+EE, cnt0, EE);
  count_kernel<<<gE, b, 0, stream>>>(ei1+EE, cnt1, EE);
  scan_kernel<<<1, 1024, 0, stream>>>(cnt0, rs0, cur0, NN);
  scan_kernel<<<1, 1024, 0, stream>>>(cnt1, rs1, cur1, NN);
  fill_kernel<<<gE, b, 0, stream>>>(ei0, ei0+EE, cur0, es0, EE);
  fill_kernel<<<gE, b, 0, stream>>>(ei1, ei1+EE, cur1, es1, EE);

  // ---- 2 hetero-GAT layers ----
  const float* xin = x_cell;
  for(int c=0;c<2;++c){
    init_bias2<<<gND, b, 0, stream>>>(W0, gat_b + (size_t)(c*2+0)*DD, gat_b + (size_t)(c*2+1)*DD);
    for(int t=0;t<2;++t){
      const int* rs = t? rs1:rs0; const int* es = t? es1:es0;
      gemm128<0><<<gGemm, b, 0, stream>>>(xin, gat_W + (size_t)(c*2+t)*DD*DD,
                                          nullptr, nullptr, nullptr, W1, NN);
      att_logits_kernel<<<gNH, b, 0, stream>>>(W1, gat_as + (size_t)(c*2+t)*HH*DHH,
                                               gat_ad + (size_t)(c*2+t)*HH*DHH, als, ald);
      gat_gather_kernel<<<gNodes, b, 0, stream>>>(W1, als, ald, rs, es, W0);
    }
    bn_stats<<<256, b, 0, stream>>>(W0, bnpart);
    bn_finalize<<<1, 128, 0, stream>>>(bnpart, bn_g + (size_t)c*DD, bn_b + (size_t)c*DD, bnstat, 256);
    float* xout = (c==0)? W2 : W1;   // x1 -> W2 ; x2 -> W1
    bn_apply_lrelu<<<gND, b, 0, stream>>>(xin, W0, bnstat, xout);
    xin = xout;
  }
  float* x2 = W1;

  // ---- HGT ----
  float* agg = (float*)d_out;   // raw acc between type passes, final agg after pass 2
  gemm128<GM_BIAS><<<gGemm, b, 0, stream>>>(x2, Wq, bq, nullptr, nullptr, W0, NN); // q -> W0
  for(int t=0;t<2;++t){
    combine_weights<<<gCW, b, 0, stream>>>(Wk, bk, a_rel + (size_t)t*HH*DHH*DHH, wck, bck);
    combine_weights<<<gCW, b, 0, stream>>>(Wv, bv, m_rel + (size_t)t*HH*DHH*DHH, wcv, bcv);
    gemm128<GM_BIAS|GM_BF16><<<gGemm, b, 0, stream>>>(x2, wck, bck, nullptr, nullptr, ktb, NN);
    gemm128<GM_BIAS|GM_BF16><<<gGemm, b, 0, stream>>>(x2, wcv, bcv, nullptr, nullptr, vtb, NN);
    if(t==0)
      hgt_fused_kernel<1><<<gNodes, b, 0, stream>>>(W0, ktb, vtb, rs0, es0, p_rel, agg, ssum);
    else
      hgt_fused_kernel<0><<<gNodes, b, 0, stream>>>(W0, ktb, vtb, rs1, es1, p_rel+HH, agg, ssum);
  }
  gemm128<GM_BIAS|GM_GELU_A><<<gGemm, b, 0, stream>>>(agg, Wo, bo, nullptr, nullptr, W2, NN); // hgt_out -> W2 (x1 dead)
  skip_mix<<<gND, b, 0, stream>>>(W2, x2, skip, W0);                  // x3a -> W0 (q dead)
  bn_stats<<<256, b, 0, stream>>>(W0, bnpart);
  bn_finalize<<<1, 128, 0, stream>>>(bnpart, bn_g + 2*DD, bn_b + 2*DD, bnstat, 256);
  bn_apply_lrelu<<<gND, b, 0, stream>>>(x2, W0, bnstat, W0);          // x3c (elementwise in-place)
  // out = gamma * (x3c + x_emb@injW + injb) + beta
  gemm128<GM_BIAS|GM_FILM><<<gGemm, b, 0, stream>>>(x_emb, injW, injb, W0, fgb, (float*)d_out, NN);
}

// Round 3
// 1186.281 us; speedup vs baseline: 1.7174x; 1.2893x over previous
//
#include <hip/hip_runtime.h>
#include <math.h>

#define NN 50000
#define DD 128
#define HH 4
#define DHH 32
#define EE 600000
#define N2 (2*NN)

typedef unsigned short u16;
typedef unsigned int   u32;

__device__ __forceinline__ float lrelu(float v){ return v > 0.f ? v : 0.2f*v; }
__device__ __forceinline__ float gelu_exact(float x){ return 0.5f*x*(1.f+erff(x*0.70710678118654752f)); }
__device__ __forceinline__ u16 f2bf(float f){
  u32 u = __float_as_uint(f);
  u32 r = (u + 0x7fffu + ((u>>16)&1u)) >> 16;
  return (u16)r;
}
__device__ __forceinline__ float bflo(u32 u){ return __uint_as_float(u<<16); }
__device__ __forceinline__ float bfhi(u32 u){ return __uint_as_float(u & 0xffff0000u); }

// ---------------- FiLM (tiny) ----------------
__global__ void film_kernel(const float* __restrict__ z, const float* __restrict__ W1, const float* __restrict__ b1,
                            const float* __restrict__ W2, const float* __restrict__ b2, float* __restrict__ gb){
  __shared__ float hsh[256];
  int j = threadIdx.x;
  float acc = b1[j];
  for(int d=0; d<DD; ++d) acc = fmaf(z[d], W1[d*256+j], acc);
  hsh[j] = gelu_exact(acc);
  __syncthreads();
  float acc2 = b2[j];
  for(int k=0;k<256;++k) acc2 = fmaf(hsh[k], W2[k*256+j], acc2);
  gb[j] = acc2;
}

// ---------------- CSR build (joint over both edge types) ----------------
__global__ void count2_kernel(const int* __restrict__ d0, const int* __restrict__ d1, int* __restrict__ jcnt){
  int e = blockIdx.x*blockDim.x+threadIdx.x;
  if(e < EE)        atomicAdd(&jcnt[d0[e]], 1);
  else if(e < 2*EE) atomicAdd(&jcnt[NN + d1[e-EE]], 1);
}

// stage 1: per-block (512 elems) sums
__global__ void scan_partial(const int* __restrict__ cnt, int* __restrict__ bsum){
  int t = threadIdx.x;
  int i0 = blockIdx.x*512 + 2*t;
  int s = 0;
  if(i0   < N2) s += cnt[i0];
  if(i0+1 < N2) s += cnt[i0+1];
  __shared__ int red[256];
  red[t]=s; __syncthreads();
  for(int off=128; off>0; off>>=1){ if(t<off) red[t]+=red[t+off]; __syncthreads(); }
  if(t==0) bsum[blockIdx.x]=red[0];
}

// stage 2: exclusive scan of block sums (nb <= 256), also writes jrs[N2]=total
__global__ void scan_blocksums(const int* __restrict__ bsum, int* __restrict__ bofs, int* __restrict__ jrs_last, int nb){
  __shared__ int sh[256];
  int t = threadIdx.x;
  int v = (t<nb)? bsum[t] : 0;
  sh[t]=v; __syncthreads();
  for(int off=1; off<256; off<<=1){
    int u = (t>=off)? sh[t-off] : 0; __syncthreads();
    sh[t]+=u; __syncthreads();
  }
  if(t<nb) bofs[t] = sh[t]-v;
  if(t==nb-1) *jrs_last = sh[t];
}

// stage 3: final exclusive scan, writes row_start and cursor
__global__ void scan_final(const int* __restrict__ cnt, const int* __restrict__ bofs,
                           int* __restrict__ jrs, int* __restrict__ jcur){
  int t = threadIdx.x;
  int i0 = blockIdx.x*512 + 2*t;
  int a = (i0   < N2)? cnt[i0]   : 0;
  int c = (i0+1 < N2)? cnt[i0+1] : 0;
  int s = a+c;
  __shared__ int sh[256];
  sh[t]=s; __syncthreads();
  for(int off=1; off<256; off<<=1){
    int u = (t>=off)? sh[t-off] : 0; __syncthreads();
    sh[t]+=u; __syncthreads();
  }
  int ex = bofs[blockIdx.x] + sh[t]-s;
  if(i0   < N2){ jrs[i0]=ex;     jcur[i0]=ex; }
  if(i0+1 < N2){ jrs[i0+1]=ex+a; jcur[i0+1]=ex+a; }
}

__global__ void fill2_kernel(const int* __restrict__ ei0, const int* __restrict__ ei1,
                             int* __restrict__ jcur, int* __restrict__ es){
  int e = blockIdx.x*blockDim.x+threadIdx.x;
  if(e < EE){
    int d = ei0[EE+e];
    int pos = atomicAdd(&jcur[d],1);
    es[pos] = ei0[e];
  } else if(e < 2*EE){
    int i = e-EE;
    int d = ei1[EE+i];
    int pos = atomicAdd(&jcur[NN+d],1);
    es[pos] = ei1[i];
  }
}

// ---------------- GEMM: C[n,128] = A[n,128] @ W[128,128] + fused epilogues ----------------
constexpr int GM_GELU_A = 1;   // gelu on A load
constexpr int GM_BIAS   = 2;   // + bias[c]
constexpr int GM_FILM   = 4;   // o += aux0[row,c]; o = aux1[c]*o + aux1[128+c]
constexpr int GM_BF16   = 8;   // bf16 output
constexpr int GM_ATT    = 16;  // GAT logits: aux0=a_s, aux1=a_d -> als/ald
constexpr int GM_SKIP   = 32;  // o = sk*o + (1-sk)*aux0[row,c], sk=sigmoid(aux2[0])

template<int MODE>
__global__ __launch_bounds__(256) void gemm128(const float* __restrict__ A, const float* __restrict__ Wg,
    const float* __restrict__ bias, const float* __restrict__ aux0, const float* __restrict__ aux1,
    const float* __restrict__ aux2, float* __restrict__ als, float* __restrict__ ald,
    void* __restrict__ Cv, int n){
  __shared__ float As[32][128];
  const int tid = threadIdx.x;
  const int row0 = blockIdx.x*32;
  {
    const float4* Ag = (const float4*)(A + (size_t)row0*DD);
    float4* As4 = (float4*)&As[0][0];
    const int maxv = (min(32, n-row0))*32;   // float4 count
    #pragma unroll
    for(int j=0;j<4;++j){
      int v = tid + j*256;
      float4 val = make_float4(0.f,0.f,0.f,0.f);
      if(v < maxv) val = Ag[v];
      if(MODE & GM_GELU_A){
        val.x = gelu_exact(val.x); val.y = gelu_exact(val.y);
        val.z = gelu_exact(val.z); val.w = gelu_exact(val.w);
      }
      As4[v] = val;
    }
  }
  __syncthreads();
  const int c2 = tid & 63;   // column pair
  const int rh = tid >> 6;   // row group (= wave id), 8 rows each
  float acc[8][2];
  #pragma unroll
  for(int r=0;r<8;++r){ acc[r][0]=0.f; acc[r][1]=0.f; }
  #pragma unroll 8
  for(int k=0;k<128;++k){
    const float2 w = *(const float2*)&Wg[k*128 + 2*c2];
    #pragma unroll
    for(int r=0;r<8;++r){
      const float a = As[rh*8+r][k];
      acc[r][0] = fmaf(a, w.x, acc[r][0]);
      acc[r][1] = fmaf(a, w.y, acc[r][1]);
    }
  }
  const int c = 2*c2;
  if(MODE & GM_ATT){
    const float2 asv = *(const float2*)&aux0[c];
    const float2 adv = *(const float2*)&aux1[c];
    const int h = (tid&63)>>4;
    #pragma unroll
    for(int r=0;r<8;++r){
      float ps = asv.x*acc[r][0] + asv.y*acc[r][1];
      float pd = adv.x*acc[r][0] + adv.y*acc[r][1];
      ps += __shfl_xor(ps,1); ps += __shfl_xor(ps,2); ps += __shfl_xor(ps,4); ps += __shfl_xor(ps,8);
      pd += __shfl_xor(pd,1); pd += __shfl_xor(pd,2); pd += __shfl_xor(pd,4); pd += __shfl_xor(pd,8);
      const int row = row0 + rh*8 + r;
      if(row < n && (tid&15)==0){ als[row*4+h]=ps; ald[row*4+h]=pd; }
    }
  }
  float b0=0.f, b1=0.f;
  if(MODE & GM_BIAS){ b0 = bias[c]; b1 = bias[c+1]; }
  float sk = 0.f;
  if(MODE & GM_SKIP) sk = 1.f/(1.f+__expf(-aux2[0]));
  #pragma unroll
  for(int r=0;r<8;++r){
    int row = row0 + rh*8 + r;
    if(row < n){
      float o0 = acc[r][0]+b0, o1 = acc[r][1]+b1;
      if(MODE & GM_SKIP){
        o0 = sk*o0 + (1.f-sk)*aux0[(size_t)row*DD + c];
        o1 = sk*o1 + (1.f-sk)*aux0[(size_t)row*DD + c + 1];
      }
      if(MODE & GM_FILM){
        o0 += aux0[(size_t)row*DD + c];
        o1 += aux0[(size_t)row*DD + c + 1];
        o0 = aux1[c]*o0 + aux1[128+c];
        o1 = aux1[c+1]*o1 + aux1[128+c+1];
      }
      if(MODE & GM_BF16){
        u16* C = (u16*)Cv;
        ((u32*)&C[(size_t)row*DD + c])[0] = (u32)f2bf(o0) | ((u32)f2bf(o1)<<16);
      } else {
        float* C = (float*)Cv;
        C[(size_t)row*DD + c]   = o0;
        C[(size_t)row*DD + c+1] = o1;
      }
    }
  }
}

// ---------------- GAT gather: one wave per node, bf16 xp table ----------------
template<int FIRST>
__global__ __launch_bounds__(256) void gat_gather_kernel(const u16* __restrict__ xp, const float* __restrict__ al_s,
    const float* __restrict__ al_d, const int* __restrict__ row_start, const int* __restrict__ esrc,
    const float* __restrict__ gb0, const float* __restrict__ gb1, float* __restrict__ acc_out){
  const int gid = blockIdx.x*blockDim.x + threadIdx.x;
  const int node = gid >> 6;
  const int lane = threadIdx.x & 63;
  if(node >= NN) return;
  const int h = lane >> 4;
  const int s0 = row_start[node], s1 = row_start[node+1];
  const float ald = al_d[node*4+h];
  float ssum = 0.f, a0=0.f, a1=0.f;
  int p = s0;
  for(; p+3<s1; p+=4){
    const int sA = esrc[p], sB = esrc[p+1], sC = esrc[p+2], sD = esrc[p+3];
    const u32 xA = *(const u32*)&xp[(size_t)sA*DD + 2*lane];
    const u32 xB = *(const u32*)&xp[(size_t)sB*DD + 2*lane];
    const u32 xC = *(const u32*)&xp[(size_t)sC*DD + 2*lane];
    const u32 xD = *(const u32*)&xp[(size_t)sD*DD + 2*lane];
    float lA = al_s[sA*4+h] + ald;  lA = lA>0.f? lA : 0.2f*lA;
    float lB = al_s[sB*4+h] + ald;  lB = lB>0.f? lB : 0.2f*lB;
    float lC = al_s[sC*4+h] + ald;  lC = lC>0.f? lC : 0.2f*lC;
    float lD = al_s[sD*4+h] + ald;  lD = lD>0.f? lD : 0.2f*lD;
    const float eA = __expf(lA), eB = __expf(lB), eC = __expf(lC), eD = __expf(lD);
    ssum += (eA+eB)+(eC+eD);
    a0 = fmaf(eA, bflo(xA), a0); a1 = fmaf(eA, bfhi(xA), a1);
    a0 = fmaf(eB, bflo(xB), a0); a1 = fmaf(eB, bfhi(xB), a1);
    a0 = fmaf(eC, bflo(xC), a0); a1 = fmaf(eC, bfhi(xC), a1);
    a0 = fmaf(eD, bflo(xD), a0); a1 = fmaf(eD, bfhi(xD), a1);
  }
  for(; p<s1; ++p){
    const int sA = esrc[p];
    const u32 xA = *(const u32*)&xp[(size_t)sA*DD + 2*lane];
    float lA = al_s[sA*4+h] + ald;  lA = lA>0.f? lA : 0.2f*lA;
    const float eA = __expf(lA);
    ssum += eA;
    a0 = fmaf(eA, bflo(xA), a0); a1 = fmaf(eA, bfhi(xA), a1);
  }
  { // self loop (appended in reference)
    float lg = al_s[node*4+h] + ald;
    lg = lg>0.f? lg : 0.2f*lg;
    const float ev = __expf(lg);
    ssum += ev;
    const u32 xr = *(const u32*)&xp[(size_t)node*DD + 2*lane];
    a0 = fmaf(ev, bflo(xr), a0); a1 = fmaf(ev, bfhi(xr), a1);
  }
  const float inv = 1.f/ssum;
  if(FIRST){
    const int cc = 2*lane;
    float2 o = make_float2(a0*inv + gb0[cc] + gb1[cc], a1*inv + gb0[cc+1] + gb1[cc+1]);
    *(float2*)&acc_out[(size_t)node*DD + cc] = o;
  } else {
    float2 o = *(float2*)&acc_out[(size_t)node*DD + 2*lane];
    o.x += a0*inv; o.y += a1*inv;
    *(float2*)&acc_out[(size_t)node*DD + 2*lane] = o;
  }
}

// ---------------- BN (deterministic two-stage) ----------------
__global__ void bn_stats(const float* __restrict__ X, float* __restrict__ part){
  int f = threadIdx.x & 127, rg = threadIdx.x>>7;
  float s=0.f, s2=0.f;
  for(int r = blockIdx.x*2+rg; r<NN; r += gridDim.x*2){
    float v = X[(size_t)r*DD+f]; s+=v; s2 = fmaf(v,v,s2);
  }
  __shared__ float ls[256], ls2[256];
  ls[threadIdx.x]=s; ls2[threadIdx.x]=s2; __syncthreads();
  if(rg==0){
    part[blockIdx.x*256 + f]       = ls[f]+ls[128+f];
    part[blockIdx.x*256 + 128 + f] = ls2[f]+ls2[128+f];
  }
}

__global__ void bn_finalize(const float* __restrict__ part, const float* __restrict__ gamma,
                            const float* __restrict__ beta, float* __restrict__ stat, int nblk){
  int f=threadIdx.x;
  float s=0.f, s2=0.f;
  for(int b=0;b<nblk;++b){ s+=part[b*256+f]; s2+=part[b*256+128+f]; }
  float mu = s/(float)NN;
  float var = s2/(float)NN - mu*mu;
  float rs = rsqrtf(var+1e-5f);
  stat[f]     = gamma[f]*rs;              // A
  stat[128+f] = beta[f] - gamma[f]*rs*mu; // B
}

// out = lrelu(xprev + A*acc + B)
__global__ void bn_apply_lrelu(const float* __restrict__ xprev, const float* __restrict__ acc,
                               const float* __restrict__ stat, float* __restrict__ out){
  int idx = blockIdx.x*blockDim.x+threadIdx.x;
  if(idx >= NN*DD) return;
  int c = idx & 127;
  float v = xprev[idx] + fmaf(stat[c], acc[idx], stat[128+c]);
  out[idx] = lrelu(v);
}

// ---------------- HGT pieces ----------------
// fold a_rel/m_rel into projection weights: Wc[c][h*32+e] = sum_d Wsrc[c][h*32+d]*rel[h][d][e]
__global__ void combine_weights(const float* __restrict__ Wsrc, const float* __restrict__ bsrc,
                                const float* __restrict__ rel, float* __restrict__ Wc, float* __restrict__ bc){
  __shared__ float rels[HH*DHH*DHH];
  for(int i=threadIdx.x;i<HH*DHH*DHH;i+=blockDim.x) rels[i]=rel[i];
  __syncthreads();
  int idx = blockIdx.x*blockDim.x+threadIdx.x;
  if(idx >= 129*128) return;
  int c = idx>>7, f = idx&127, h=f>>5, e=f&31;
  const float* srcp = (c<128)? &Wsrc[c*128 + h*DHH] : &bsrc[h*DHH];
  const float* m = &rels[h*DHH*DHH + e];
  float s=0.f;
  #pragma unroll
  for(int d=0;d<DHH;++d) s = fmaf(srcp[d], m[d*DHH], s);
  if(c<128) Wc[c*128+f]=s; else bc[f]=s;
}

// fused HGT edge phase for one edge type: logits + exp + weighted-V accumulate.
template<int FIRST>
__global__ __launch_bounds__(256) void hgt_fused_kernel(const float* __restrict__ q,
    const u16* __restrict__ ktb, const u16* __restrict__ vtb,
    const int* __restrict__ row_start, const int* __restrict__ esrc,
    const float* __restrict__ p_rel_t, float* __restrict__ acc, float* __restrict__ ssum_buf){
  const int gid = blockIdx.x*blockDim.x + threadIdx.x;
  const int node = gid >> 6;
  const int lane = threadIdx.x & 63;
  if(node >= NN) return;
  const int h = lane >> 4;
  const float2 qv = *(const float2*)&q[(size_t)node*DD + 2*lane];
  const float scale = p_rel_t[h]*0.17677669529663687f; // p_rel / sqrt(32)
  const int s0=row_start[node], s1=row_start[node+1];
  float ssum=0.f, a0=0.f, a1=0.f;
  int p=s0;
  for(; p+3<s1; p+=4){
    const int sA = esrc[p], sB = esrc[p+1], sC = esrc[p+2], sD = esrc[p+3];
    const u32 kA = *(const u32*)&ktb[(size_t)sA*DD + 2*lane];
    const u32 kB = *(const u32*)&ktb[(size_t)sB*DD + 2*lane];
    const u32 kC = *(const u32*)&ktb[(size_t)sC*DD + 2*lane];
    const u32 kD = *(const u32*)&ktb[(size_t)sD*DD + 2*lane];
    const u32 vA = *(const u32*)&vtb[(size_t)sA*DD + 2*lane];
    const u32 vB = *(const u32*)&vtb[(size_t)sB*DD + 2*lane];
    const u32 vC = *(const u32*)&vtb[(size_t)sC*DD + 2*lane];
    const u32 vD = *(const u32*)&vtb[(size_t)sD*DD + 2*lane];
    float pA = qv.x*bflo(kA) + qv.y*bfhi(kA);
    float pB = qv.x*bflo(kB) + qv.y*bfhi(kB);
    float pC = qv.x*bflo(kC) + qv.y*bfhi(kC);
    float pD = qv.x*bflo(kD) + qv.y*bfhi(kD);
    pA += __shfl_xor(pA,1); pB += __shfl_xor(pB,1); pC += __shfl_xor(pC,1); pD += __shfl_xor(pD,1);
    pA += __shfl_xor(pA,2); pB += __shfl_xor(pB,2); pC += __shfl_xor(pC,2); pD += __shfl_xor(pD,2);
    pA += __shfl_xor(pA,4); pB += __shfl_xor(pB,4); pC += __shfl_xor(pC,4); pD += __shfl_xor(pD,4);
    pA += __shfl_xor(pA,8); pB += __shfl_xor(pB,8); pC += __shfl_xor(pC,8); pD += __shfl_xor(pD,8);
    const float eA = __expf(pA*scale), eB = __expf(pB*scale);
    const float eC = __expf(pC*scale), eD = __expf(pD*scale);
    ssum += (eA+eB)+(eC+eD);
    a0 = fmaf(eA, bflo(vA), a0); a1 = fmaf(eA, bfhi(vA), a1);
    a0 = fmaf(eB, bflo(vB), a0); a1 = fmaf(eB, bfhi(vB), a1);
    a0 = fmaf(eC, bflo(vC), a0); a1 = fmaf(eC, bfhi(vC), a1);
    a0 = fmaf(eD, bflo(vD), a0); a1 = fmaf(eD, bfhi(vD), a1);
  }
  for(; p<s1; ++p){
    const int sA = esrc[p];
    const u32 kA = *(const u32*)&ktb[(size_t)sA*DD + 2*lane];
    const u32 vA = *(const u32*)&vtb[(size_t)sA*DD + 2*lane];
    float pA = qv.x*bflo(kA) + qv.y*bfhi(kA);
    pA += __shfl_xor(pA,1);
    pA += __shfl_xor(pA,2);
    pA += __shfl_xor(pA,4);
    pA += __shfl_xor(pA,8);
    const float eA = __expf(pA*scale);
    ssum += eA;
    a0 = fmaf(eA, bflo(vA), a0); a1 = fmaf(eA, bfhi(vA), a1);
  }
  if(FIRST){
    *(float2*)&acc[(size_t)node*DD + 2*lane] = make_float2(a0, a1);
    if((lane&15)==0) ssum_buf[node*4+h] = ssum;
  } else {
    const float tot = ssum + ssum_buf[node*4+h];
    const float inv = tot>0.f ? 1.f/tot : 0.f;
    float2 prev = *(float2*)&acc[(size_t)node*DD + 2*lane];
    prev.x = (prev.x + a0)*inv;
    prev.y = (prev.y + a1)*inv;
    *(float2*)&acc[(size_t)node*DD + 2*lane] = prev;
  }
}

// ---------------- host ----------------
extern "C" void kernel_launch(void* const* d_in, const int* in_sizes, int n_in,
                              void* d_out, int out_size, void* d_ws, size_t ws_size,
                              hipStream_t stream){
  const float* x_cell = (const float*)d_in[0];
  const float* z_h    = (const float*)d_in[1];
  const float* x_emb  = (const float*)d_in[2];
  const int*   ei0    = (const int*)d_in[3];
  const int*   ei1    = (const int*)d_in[4];
  const float* gat_W  = (const float*)d_in[5];
  const float* gat_as = (const float*)d_in[6];
  const float* gat_ad = (const float*)d_in[7];
  const float* gat_b  = (const float*)d_in[8];
  const float* bn_g   = (const float*)d_in[9];
  const float* bn_b   = (const float*)d_in[10];
  const float* Wk = (const float*)d_in[11];
  const float* bk = (const float*)d_in[12];
  const float* Wq = (const float*)d_in[13];
  const float* bq = (const float*)d_in[14];
  const float* Wv = (const float*)d_in[15];
  const float* bv = (const float*)d_in[16];
  const float* a_rel = (const float*)d_in[17];
  const float* m_rel = (const float*)d_in[18];
  const float* p_rel = (const float*)d_in[19];
  const float* Wo = (const float*)d_in[20];
  const float* bo = (const float*)d_in[21];
  const float* skip = (const float*)d_in[22];
  const float* injW = (const float*)d_in[23];
  const float* injb = (const float*)d_in[24];
  const float* fW1 = (const float*)d_in[25];
  const float* fb1 = (const float*)d_in[26];
  const float* fW2 = (const float*)d_in[27];
  const float* fb2 = (const float*)d_in[28];

  constexpr size_t SLOT = (size_t)NN*DD;   // 6,400,000
  float* ws = (float*)d_ws;
  float* W0 = ws;
  float* W1 = W0 + SLOT;
  float* W2 = W1 + SLOT;
  u16* ktb  = (u16*)(W2 + SLOT);        // NN*DD bf16 (doubles as GAT xp table)
  u16* vtb  = ktb + SLOT;               // NN*DD bf16
  float* als    = (float*)(vtb + SLOT);
  float* ald    = als + (size_t)NN*HH;
  float* ssum   = ald + (size_t)NN*HH;
  float* bnpart = ssum + (size_t)NN*HH;
  float* bnstat = bnpart + 256*256;
  float* fgb    = bnstat + 256;
  float* wck    = fgb + 256;
  float* bck    = wck + 128*128;
  float* wcv    = bck + 128;
  float* bcv    = wcv + 128*128;
  int* jcnt = (int*)(bcv + 128);   // 2*NN
  int* jrs  = jcnt + N2;           // 2*NN + 1
  int* jcur = jrs + N2 + 2;        // 2*NN
  int* bsum = jcur + N2;           // 256
  int* bofs = bsum + 256;          // 256
  int* es   = bofs + 256;          // 2*EE
  size_t needed = (size_t)((char*)(es + 2*EE) - (char*)d_ws);
  if(ws_size < needed) return;  // insufficient scratch: fail loud (poisoned d_out)

  const int TB = 256;
  dim3 b(TB);
  const int gE2    = (2*EE + TB - 1)/TB;
  const int gND    = (NN*DD + TB - 1)/TB;
  const int gNodes = (NN + 3)/4;          // 4 waves/block, wave per node
  const int gGemm  = (NN + 31)/32;
  const int gCW    = (129*128 + TB - 1)/TB;
  const int gScan  = (N2 + 511)/512;      // 196 blocks

  // FiLM params (only depend on z_h)
  film_kernel<<<1, 256, 0, stream>>>(z_h, fW1, fb1, fW2, fb2, fgb);

  // joint CSR by dst for both edge types
  hipMemsetAsync(jcnt, 0, N2*sizeof(int), stream);
  count2_kernel<<<gE2, b, 0, stream>>>(ei0+EE, ei1+EE, jcnt);
  scan_partial<<<gScan, b, 0, stream>>>(jcnt, bsum);
  scan_blocksums<<<1, 256, 0, stream>>>(bsum, bofs, jrs + N2, gScan);
  scan_final<<<gScan, b, 0, stream>>>(jcnt, bofs, jrs, jcur);
  fill2_kernel<<<gE2, b, 0, stream>>>(ei0, ei1, jcur, es);

  // ---- 2 hetero-GAT layers ----
  const float* xin = x_cell;
  u16* gtb = ktb;   // bf16 xp table (reuses ktb slot during GAT)
  for(int c=0;c<2;++c){
    for(int t=0;t<2;++t){
      const int* rs = jrs + t*NN;
      gemm128<GM_ATT|GM_BF16><<<gGemm, b, 0, stream>>>(xin, gat_W + (size_t)(c*2+t)*DD*DD,
          nullptr, gat_as + (size_t)(c*2+t)*HH*DHH, gat_ad + (size_t)(c*2+t)*HH*DHH,
          nullptr, als, ald, gtb, NN);
      if(t==0)
        gat_gather_kernel<1><<<gNodes, b, 0, stream>>>(gtb, als, ald, rs, es,
            gat_b + (size_t)(c*2+0)*DD, gat_b + (size_t)(c*2+1)*DD, W0);
      else
        gat_gather_kernel<0><<<gNodes, b, 0, stream>>>(gtb, als, ald, rs, es,
            nullptr, nullptr, W0);
    }
    bn_stats<<<256, b, 0, stream>>>(W0, bnpart);
    bn_finalize<<<1, 128, 0, stream>>>(bnpart, bn_g + (size_t)c*DD, bn_b + (size_t)c*DD, bnstat, 256);
    float* xout = (c==0)? W1 : W2;   // x1 -> W1 ; x2 -> W2
    bn_apply_lrelu<<<gND, b, 0, stream>>>(xin, W0, bnstat, xout);
    xin = xout;
  }
  float* x2 = W2;

  // ---- HGT ----
  float* agg = (float*)d_out;   // raw acc between type passes, final agg after pass 2
  gemm128<GM_BIAS><<<gGemm, b, 0, stream>>>(x2, Wq, bq, nullptr, nullptr, nullptr,
                                            nullptr, nullptr, W0, NN); // q -> W0
  for(int t=0;t<2;++t){
    combine_weights<<<gCW, b, 0, stream>>>(Wk, bk, a_rel + (size_t)t*HH*DHH*DHH, wck, bck);
    combine_weights<<<gCW, b, 0, stream>>>(Wv, bv, m_rel + (size_t)t*HH*DHH*DHH, wcv, bcv);
    gemm128<GM_BIAS|GM_BF16><<<gGemm, b, 0, stream>>>(x2, wck, bck, nullptr, nullptr, nullptr,
                                                      nullptr, nullptr, ktb, NN);
    gemm128<GM_BIAS|GM_BF16><<<gGemm, b, 0, stream>>>(x2, wcv, bcv, nullptr, nullptr, nullptr,
                                                      nullptr, nullptr, vtb, NN);
    if(t==0)
      hgt_fused_kernel<1><<<gNodes, b, 0, stream>>>(W0, ktb, vtb, jrs, es, p_rel, agg, ssum);
    else
      hgt_fused_kernel<0><<<gNodes, b, 0, stream>>>(W0, ktb, vtb, jrs+NN, es, p_rel+HH, agg, ssum);
  }
  // hgt_out with fused skip-mix: W1 = sk*(gelu(agg)@Wo+bo) + (1-sk)*x2   (x1 in W1 is dead)
  gemm128<GM_BIAS|GM_GELU_A|GM_SKIP><<<gGemm, b, 0, stream>>>(agg, Wo, bo, x2, nullptr, skip,
                                                              nullptr, nullptr, W1, NN);
  bn_stats<<<256, b, 0, stream>>>(W1, bnpart);
  bn_finalize<<<1, 128, 0, stream>>>(bnpart, bn_g + 2*DD, bn_b + 2*DD, bnstat, 256);
  bn_apply_lrelu<<<gND, b, 0, stream>>>(x2, W1, bnstat, W1);          // x3c (elementwise, in place)
  // out = gamma * (x3c + x_emb@injW + injb) + beta
  gemm128<GM_BIAS|GM_FILM><<<gGemm, b, 0, stream>>>(x_emb, injW, injb, W1, fgb, nullptr,
                                                    nullptr, nullptr, (float*)d_out, NN);
}